// Round 7
// baseline (489.492 us; speedup 1.0000x reference)
//
#include <hip/hip_runtime.h>
#include <hip/hip_bf16.h>
#include <cstdint>

// SimpleGAT on MI355X. Round 7:
//   R6 @325us; gemm1 61us (Mfma 20%, VALU 21%, occ 26%) -- per-kt barrier
//   drains vmcnt(0), exposing the A fp32 load latency + cvt chain each kt.
//   agg FETCH ~156MB = 8-XCD dup of random gathers (structural).
// Changes:
//   1. gemm: A software-pipelined one kt ahead (fetch kt+1 raw, cvt kt's data
//      fetched last iter -> latency hidden behind compute); RT=2 row tiles
//      (48 MFMA / 16 ds_read per kt); gemm2 A pre-split (no cvt at all).
//   2. agg1/agg2 XCD channel-sharding: block=(node, cq), cq=blockIdx%8(/4);
//      round-robin block->XCD => each XCD touches a 2.56MB slice of h1b/h2b
//      -> L2-resident gathers. One wave/block, shuffle-broadcast alpha,
//      cq==0 writes alpha float4.
//   3. agg1 emits h1e as hi/lo bf16 split; merged memsets+swizzles.
//
// MFMA 16x16x32 bf16 layouts (verified R3-R6):
//   A: lane holds A[m=lane&15][k=(lane>>4)*8 + j], j=0..7
//   B: lane holds B[k=(lane>>4)*8 + j][n=lane&15]   (pre-swizzled contiguous)
//   C/D: col = lane&15, row = (lane>>4)*4 + reg

#define NNODES 20000
#define NEDGES 320000
#define ETOT   340000   // NEDGES + NNODES self loops
#define F1     512      // HEADS*HID
#define F2     256      // OUT_CH
#define HEADS  4

typedef __bf16 bf16;
typedef __attribute__((ext_vector_type(8))) __bf16 bf16x8;
typedef __attribute__((ext_vector_type(4))) float f32x4;

__device__ __forceinline__ void gload_lds16(const void* g, void* l) {
    __builtin_amdgcn_global_load_lds(
        (const __attribute__((address_space(1))) void*)g,
        (__attribute__((address_space(3))) void*)l, 16, 0, 0);
}

// ---------------- CSR build ----------------
__global__ void deg_count(const int* __restrict__ ei, int* __restrict__ deg) {
    int e = blockIdx.x * blockDim.x + threadIdx.x;
    if (e >= ETOT) return;
    int dst = (e < NEDGES) ? ei[NEDGES + e] : (e - NEDGES);
    atomicAdd(&deg[dst], 1);
}

__global__ void scan_deg(const int* __restrict__ deg, int* __restrict__ offs,
                         int* __restrict__ cur) {
    __shared__ int sums[1024];
    const int t = threadIdx.x;
    const int PER = 20;
    int base = t * PER;
    int local[PER];
    int run = 0;
#pragma unroll
    for (int j = 0; j < PER; j++) {
        int i = base + j;
        int v = (i < NNODES) ? deg[i] : 0;
        local[j] = run;
        run += v;
    }
    sums[t] = run;
    __syncthreads();
    for (int o = 1; o < 1024; o <<= 1) {
        int v = (t >= o) ? sums[t - o] : 0;
        __syncthreads();
        sums[t] += v;
        __syncthreads();
    }
    int texcl = (t == 0) ? 0 : sums[t - 1];
#pragma unroll
    for (int j = 0; j < PER; j++) {
        int i = base + j;
        if (i < NNODES) {
            int e = texcl + local[j];
            cur[i] = e;
            offs[i] = e;
        }
    }
    if (t == 1023) offs[NNODES] = sums[1023];
}

__global__ void fill_csr(const int* __restrict__ ei, int* __restrict__ cur,
                         int* __restrict__ csr_src, int* __restrict__ csr_eid) {
    int e = blockIdx.x * blockDim.x + threadIdx.x;
    if (e >= ETOT) return;
    int src, dst;
    if (e < NEDGES) { src = ei[e]; dst = ei[NEDGES + e]; }
    else            { src = dst = e - NEDGES; }
    int p = atomicAdd(&cur[dst], 1);
    csr_src[p] = src;
    csr_eid[p] = e;
}

// ---------------- W swizzle (both weights in one launch) ----------------
__device__ __forceinline__ void swz(const float* __restrict__ W, bf16* __restrict__ Wh,
                                    bf16* __restrict__ Wl, int N, int idx) {
    int lane = idx & 63;
    int tile = idx >> 6;
    int NT = N >> 4;
    int kt = tile / NT, nt = tile - kt * NT;
    int krow = kt * 32 + (lane >> 4) * 8;
    int col  = nt * 16 + (lane & 15);
    union { bf16 b[8]; uint4 u; } hi, lo;
#pragma unroll
    for (int j = 0; j < 8; j++) {
        float w = W[(size_t)(krow + j) * N + col];
        bf16 h = (bf16)w;
        hi.b[j] = h;
        lo.b[j] = (bf16)(w - (float)h);
    }
    *(uint4*)(Wh + (size_t)idx * 8) = hi.u;
    *(uint4*)(Wl + (size_t)idx * 8) = lo.u;
}

__global__ void swizzle_both(const float* __restrict__ W1, bf16* __restrict__ W1h,
                             bf16* __restrict__ W1l, const float* __restrict__ W2,
                             bf16* __restrict__ W2h, bf16* __restrict__ W2l) {
    int idx = blockIdx.x * blockDim.x + threadIdx.x;
    const int t1 = (512 * 512) >> 3;    // 32768
    const int t2 = (512 * 256) >> 3;    // 16384
    if (idx < t1) swz(W1, W1h, W1l, 512, idx);
    else if (idx < t1 + t2) swz(W2, W2h, W2l, 256, idx - t1);
}

// ------- split-bf16 MFMA GEMM, LDS-staged B, pipelined A, fused attn epilogue ----
// block = 4 waves x (RT*16) rows; 8 col-tiles = 128 cols. LDS dbuf 2x16KB.
template <int K, int N, int RT, bool ASPLIT>
__global__ __launch_bounds__(256) void gemm_fused(const float* __restrict__ A,
                                                  const bf16* __restrict__ Ah,
                                                  const bf16* __restrict__ Al,
                                                  const bf16* __restrict__ Bh,
                                                  const bf16* __restrict__ Bl,
                                                  bf16* __restrict__ Cb,
                                                  const float* __restrict__ asrc,
                                                  const float* __restrict__ adst,
                                                  float* __restrict__ as_out,
                                                  float* __restrict__ ad_out, int M) {
    __shared__ __align__(16) char smem[2][16384];
    const int lane = threadIdx.x & 63;
    const int wave = threadIdx.x >> 6;
    const int row_base = blockIdx.x * (4 * RT * 16) + wave * (RT * 16);
    const int colt0 = blockIdx.y * 8;
    constexpr int NT = N / 16;

    const char* hbase = (const char*)Bh + (size_t)colt0 * 1024;
    const char* lbase = (const char*)Bl + (size_t)colt0 * 1024;
    auto stage = [&](int kt, int buf) {
        size_t kb = (size_t)kt * NT * 1024;
#pragma unroll
        for (int q = 0; q < 4; q++) {
            int off = wave * 4096 + q * 1024;
            const char* src = (off < 8192) ? (hbase + kb + off)
                                           : (lbase + kb + (off - 8192));
            gload_lds16(src + lane * 16, &smem[buf][off]);
        }
    };

    const float* aptr[RT];
    const bf16 *ahp[RT], *alp[RT];
#pragma unroll
    for (int t = 0; t < RT; t++) {
        int r = row_base + t * 16 + (lane & 15);
        if (r >= M) r = M - 1;
        if constexpr (ASPLIT) {
            ahp[t] = Ah + (size_t)r * K + ((lane >> 4) * 8);
            alp[t] = Al + (size_t)r * K + ((lane >> 4) * 8);
        } else {
            aptr[t] = A + (size_t)r * K + ((lane >> 4) * 8);
        }
    }

    float4 nf[RT][2];              // next A raw (fp32 path)
    bf16x8 nah[RT], nal[RT];       // next A (pre-split path)
    auto fetchA = [&](int kt) {
#pragma unroll
        for (int t = 0; t < RT; t++) {
            if constexpr (ASPLIT) {
                nah[t] = *(const bf16x8*)(ahp[t] + kt * 32);
                nal[t] = *(const bf16x8*)(alp[t] + kt * 32);
            } else {
                nf[t][0] = *(const float4*)(aptr[t] + kt * 32);
                nf[t][1] = *(const float4*)(aptr[t] + kt * 32 + 4);
            }
        }
    };
    bf16x8 cah[RT], cal[RT];
    auto cvtA = [&]() {
#pragma unroll
        for (int t = 0; t < RT; t++) {
            if constexpr (ASPLIT) {
                cah[t] = nah[t];
                cal[t] = nal[t];
            } else {
                float av[8];
                *(float4*)(av)     = nf[t][0];
                *(float4*)(av + 4) = nf[t][1];
#pragma unroll
                for (int j = 0; j < 8; j++) {
                    bf16 h = (bf16)av[j];
                    cah[t][j] = h;
                    cal[t][j] = (bf16)(av[j] - (float)h);
                }
            }
        }
    };

    f32x4 acc[RT][8] = {};
    stage(0, 0);
    fetchA(0);
    __syncthreads();
    for (int kt = 0; kt < K / 32; ++kt) {
        cvtA();                               // consumes fetchA(kt) (already drained)
        if (kt + 1 < K / 32) {
            stage(kt + 1, (kt + 1) & 1);      // issued early: full iter in flight
            fetchA(kt + 1);
        }
        const char* bb = smem[kt & 1];
#pragma unroll
        for (int c = 0; c < 8; c++) {
            bf16x8 bh = *(const bf16x8*)(bb + c * 1024 + lane * 16);
            bf16x8 bl = *(const bf16x8*)(bb + 8192 + c * 1024 + lane * 16);
#pragma unroll
            for (int t = 0; t < RT; t++) {
                acc[t][c] = __builtin_amdgcn_mfma_f32_16x16x32_bf16(cah[t], bh, acc[t][c], 0, 0, 0);
                acc[t][c] = __builtin_amdgcn_mfma_f32_16x16x32_bf16(cah[t], bl, acc[t][c], 0, 0, 0);
                acc[t][c] = __builtin_amdgcn_mfma_f32_16x16x32_bf16(cal[t], bh, acc[t][c], 0, 0, 0);
            }
        }
        __syncthreads();
    }

    const int qrow = (lane >> 4) * 4;
    const int col15 = lane & 15;
#pragma unroll
    for (int t = 0; t < RT; t++)
#pragma unroll
        for (int c = 0; c < 8; c++)
#pragma unroll
            for (int r = 0; r < 4; r++) {
                int rr = row_base + t * 16 + qrow + r;
                if (rr < M)
                    Cb[(size_t)rr * N + (colt0 + c) * 16 + col15] = (bf16)acc[t][c][r];
            }

    // fused attention-coefficient dots over the block's 128 cols
    float ss[RT][4] = {}, sd[RT][4] = {};
#pragma unroll
    for (int c = 0; c < 8; c++) {
        int cw = blockIdx.y * 128 + c * 16 + col15;
        float was = asrc[cw];
        float wad = adst[cw];
#pragma unroll
        for (int t = 0; t < RT; t++)
#pragma unroll
            for (int r = 0; r < 4; r++) {
                ss[t][r] += acc[t][c][r] * was;
                sd[t][r] += acc[t][c][r] * wad;
            }
    }
#pragma unroll
    for (int o = 1; o < 16; o <<= 1)
#pragma unroll
        for (int t = 0; t < RT; t++)
#pragma unroll
            for (int r = 0; r < 4; r++) {
                ss[t][r] += __shfl_xor(ss[t][r], o);
                sd[t][r] += __shfl_xor(sd[t][r], o);
            }
    if (col15 == 0) {
#pragma unroll
        for (int t = 0; t < RT; t++)
#pragma unroll
            for (int r = 0; r < 4; r++) {
                int rr = row_base + t * 16 + qrow + r;
                if (rr < M) {
                    if constexpr (N == 512) {       // block cols == one head
                        as_out[rr * 4 + blockIdx.y] = ss[t][r];
                        ad_out[rr * 4 + blockIdx.y] = sd[t][r];
                    } else {                         // half head: atomic reduce
                        atomicAdd(&as_out[rr], ss[t][r]);
                        atomicAdd(&ad_out[rr], sd[t][r]);
                    }
                }
            }
    }
}

// -------- layer 1 softmax + aggregate: XCD-sharded, one wave per (node, cq) ------
// blockIdx.x = n*8 + cq; cq selects a 64-channel slice (head h = cq>>1).
// Round-robin block->XCD => XCD x sees only cq==x%8 => 2.56MB h1b slice in L2.
__global__ __launch_bounds__(64) void agg1(const bf16* __restrict__ h1b,
                                           const float* __restrict__ as1,
                                           const float* __restrict__ ad1,
                                           const int* __restrict__ offs,
                                           const int* __restrict__ csrS,
                                           const int* __restrict__ csrE,
                                           const float* __restrict__ b1,
                                           float* __restrict__ alpha1,
                                           bf16* __restrict__ h1eh,
                                           bf16* __restrict__ h1el) {
    const int n = blockIdx.x >> 3, cq = blockIdx.x & 7;
    const int lane = threadIdx.x;
    const int h = cq >> 1;
    const int beg = offs[n];
    const int deg = offs[n + 1] - beg;

    float4 ad4 = *(const float4*)(ad1 + n * 4);
    const float adn[4] = {ad4.x, ad4.y, ad4.z, ad4.w};

    // softmax pass 1: max (first chunk cached)
    float v0[4] = {};
    int s0 = 0, e0 = 0;
    float mx[4] = {-3e38f, -3e38f, -3e38f, -3e38f};
    for (int idx = lane; idx < deg; idx += 64) {
        int s = csrS[beg + idx];
        float4 a4 = *(const float4*)(as1 + s * 4);
        float v[4] = {a4.x + adn[0], a4.y + adn[1], a4.z + adn[2], a4.w + adn[3]};
#pragma unroll
        for (int k = 0; k < 4; k++) {
            v[k] = v[k] > 0.f ? v[k] : 0.2f * v[k];
            mx[k] = fmaxf(mx[k], v[k]);
        }
        if (idx == lane) {
            s0 = s; e0 = csrE[beg + idx];
#pragma unroll
            for (int k = 0; k < 4; k++) v0[k] = v[k];
        }
    }
#pragma unroll
    for (int o = 1; o < 64; o <<= 1)
#pragma unroll
        for (int k = 0; k < 4; k++) mx[k] = fmaxf(mx[k], __shfl_xor(mx[k], o));

    // pass 2: denom
    float ex0[4] = {0.f, 0.f, 0.f, 0.f};
    float ls[4] = {0.f, 0.f, 0.f, 0.f};
    if (lane < deg) {
#pragma unroll
        for (int k = 0; k < 4; k++) { ex0[k] = __expf(v0[k] - mx[k]); ls[k] = ex0[k]; }
    }
    for (int idx = lane + 64; idx < deg; idx += 64) {
        int s = csrS[beg + idx];
        float4 a4 = *(const float4*)(as1 + s * 4);
        float v[4] = {a4.x + adn[0], a4.y + adn[1], a4.z + adn[2], a4.w + adn[3]};
#pragma unroll
        for (int k = 0; k < 4; k++) {
            v[k] = v[k] > 0.f ? v[k] : 0.2f * v[k];
            ls[k] += __expf(v[k] - mx[k]);
        }
    }
#pragma unroll
    for (int o = 1; o < 64; o <<= 1)
#pragma unroll
        for (int k = 0; k < 4; k++) ls[k] += __shfl_xor(ls[k], o);
    float rden[4];
#pragma unroll
    for (int k = 0; k < 4; k++) rden[k] = 1.f / ls[k];

    // aggregate this block's 64-channel slice; shuffle-broadcast alphas
    float acc = 0.f;
    const int ch = (cq << 6) + lane;
    for (int base = 0; base < deg; base += 64) {
        int idx = base + lane;
        int cnt = min(64, deg - base);
        float myal = 0.f;
        int mys = 0;
        if (idx < deg) {
            float al[4];
            int s, e;
            if (base == 0) {
                s = s0; e = e0;
#pragma unroll
                for (int k = 0; k < 4; k++) al[k] = ex0[k] * rden[k];
            } else {
                s = csrS[beg + idx];
                e = csrE[beg + idx];
                float4 a4 = *(const float4*)(as1 + s * 4);
                float v[4] = {a4.x + adn[0], a4.y + adn[1], a4.z + adn[2], a4.w + adn[3]};
#pragma unroll
                for (int k = 0; k < 4; k++) {
                    v[k] = v[k] > 0.f ? v[k] : 0.2f * v[k];
                    al[k] = __expf(v[k] - mx[k]) * rden[k];
                }
            }
            mys = s;
            myal = al[h];
            if (cq == 0)
                *(float4*)(alpha1 + (size_t)e * 4) = make_float4(al[0], al[1], al[2], al[3]);
        }
        for (int i = 0; i < cnt; i++) {
            int s = __shfl(mys, i);
            float a = __shfl(myal, i);
            acc += a * (float)h1b[(size_t)s * F1 + ch];
        }
    }
    float t = acc + b1[ch];
    t = t > 0.f ? t : expm1f(t);     // ELU
    bf16 hi = (bf16)t;
    h1eh[(size_t)n * F1 + ch] = hi;
    h1el[(size_t)n * F1 + ch] = (bf16)(t - (float)hi);
}

// -------- layer 2 softmax + aggregate: XCD-sharded (4 slices), final out --------
__global__ __launch_bounds__(64) void agg2(const bf16* __restrict__ h2b,
                                           const float* __restrict__ as2,
                                           const float* __restrict__ ad2,
                                           const int* __restrict__ offs,
                                           const int* __restrict__ csrS,
                                           const int* __restrict__ csrE,
                                           const float* __restrict__ b2,
                                           float* __restrict__ alpha2,
                                           float* __restrict__ out) {
    const int n = blockIdx.x >> 2, cq = blockIdx.x & 3;
    const int lane = threadIdx.x;
    const int beg = offs[n];
    const int deg = offs[n + 1] - beg;

    const float adn = ad2[n];

    float v0 = 0.f;
    int s0 = 0, e0 = 0;
    float mx = -3e38f;
    for (int idx = lane; idx < deg; idx += 64) {
        int s = csrS[beg + idx];
        float v = as2[s] + adn;
        v = v > 0.f ? v : 0.2f * v;
        mx = fmaxf(mx, v);
        if (idx == lane) { s0 = s; e0 = csrE[beg + idx]; v0 = v; }
    }
#pragma unroll
    for (int o = 1; o < 64; o <<= 1) mx = fmaxf(mx, __shfl_xor(mx, o));

    float ex0 = 0.f, ls = 0.f;
    if (lane < deg) { ex0 = __expf(v0 - mx); ls = ex0; }
    for (int idx = lane + 64; idx < deg; idx += 64) {
        int s = csrS[beg + idx];
        float v = as2[s] + adn;
        v = v > 0.f ? v : 0.2f * v;
        ls += __expf(v - mx);
    }
#pragma unroll
    for (int o = 1; o < 64; o <<= 1) ls += __shfl_xor(ls, o);
    float rden = 1.f / ls;

    float acc = 0.f;
    const int ch = (cq << 6) + lane;
    for (int base = 0; base < deg; base += 64) {
        int idx = base + lane;
        int cnt = min(64, deg - base);
        float myal = 0.f;
        int mys = 0;
        if (idx < deg) {
            float a;
            int s, e;
            if (base == 0) { s = s0; e = e0; a = ex0 * rden; }
            else {
                s = csrS[beg + idx];
                e = csrE[beg + idx];
                float v = as2[s] + adn;
                v = v > 0.f ? v : 0.2f * v;
                a = __expf(v - mx) * rden;
            }
            mys = s;
            myal = a;
            if (cq == 0) alpha2[e] = a;
        }
        for (int i = 0; i < cnt; i++) {
            int s = __shfl(mys, i);
            float a = __shfl(myal, i);
            acc += a * (float)h2b[(size_t)s * F2 + ch];
        }
    }
    out[(size_t)n * F2 + ch] = acc + b2[ch];
}

// ---------------- launch ----------------
extern "C" void kernel_launch(void* const* d_in, const int* in_sizes, int n_in,
                              void* d_out, int out_size, void* d_ws, size_t ws_size,
                              hipStream_t stream) {
    const float* x      = (const float*)d_in[0];
    const int*   ei     = (const int*)d_in[1];
    const float* W1     = (const float*)d_in[2];
    const float* a_src1 = (const float*)d_in[3];
    const float* a_dst1 = (const float*)d_in[4];
    const float* b1     = (const float*)d_in[5];
    const float* W2     = (const float*)d_in[6];
    const float* a_src2 = (const float*)d_in[7];
    const float* a_dst2 = (const float*)d_in[8];
    const float* b2     = (const float*)d_in[9];

    char* ws = (char*)d_ws;
    size_t off = 0;
    auto alloc = [&](size_t bytes) -> char* {
        char* p = ws + off;
        off += (bytes + 255) & ~(size_t)255;
        return p;
    };
    bf16*  h1b  = (bf16*) alloc((size_t)NNODES * F1 * 2);   // 20.5 MB
    bf16*  h2b  = (bf16*) alloc((size_t)NNODES * F2 * 2);   // 10.2 MB
    bf16*  h1eh = (bf16*) alloc((size_t)NNODES * F1 * 2);   // 20.5 MB
    bf16*  h1el = (bf16*) alloc((size_t)NNODES * F1 * 2);   // 20.5 MB
    float* as1  = (float*)alloc((size_t)NNODES * 4 * 4);
    float* ad1  = (float*)alloc((size_t)NNODES * 4 * 4);
    // deg, as2, ad2 contiguous: single memset covers all three (incl. padding)
    int*   deg  = (int*)  alloc((size_t)NNODES * 4);
    float* as2  = (float*)alloc((size_t)NNODES * 4);
    float* ad2  = (float*)alloc((size_t)NNODES * 4);
    bf16*  W1h  = (bf16*) alloc((size_t)512 * 512 * 2);
    bf16*  W1l  = (bf16*) alloc((size_t)512 * 512 * 2);
    bf16*  W2h  = (bf16*) alloc((size_t)512 * 256 * 2);
    bf16*  W2l  = (bf16*) alloc((size_t)512 * 256 * 2);
    int*   offs = (int*)  alloc((size_t)(NNODES + 1) * 4);
    int*   cur  = (int*)  alloc((size_t)NNODES * 4);
    int*   csrS = (int*)  alloc((size_t)ETOT * 4);
    int*   csrE = (int*)  alloc((size_t)ETOT * 4);

    float* out2   = (float*)d_out;                      // [20000,256]
    float* alpha1 = out2 + (size_t)NNODES * F2;         // [340000,4]
    float* alpha2 = alpha1 + (size_t)ETOT * HEADS;      // [340000]

    hipMemsetAsync(deg, 0, (size_t)((char*)ad2 - (char*)deg) + NNODES * 4, stream);
    deg_count<<<(ETOT + 255) / 256, 256, 0, stream>>>(ei, deg);
    scan_deg<<<1, 1024, 0, stream>>>(deg, offs, cur);
    fill_csr<<<(ETOT + 255) / 256, 256, 0, stream>>>(ei, cur, csrS, csrE);

    swizzle_both<<<(49152 + 255) / 256, 256, 0, stream>>>(W1, W1h, W1l, W2, W2h, W2l);

    gemm_fused<512, 512, 2, false><<<dim3(157, 4), 256, 0, stream>>>(
        x, nullptr, nullptr, W1h, W1l, h1b, a_src1, a_dst1, as1, ad1, NNODES);
    agg1<<<NNODES * 8, 64, 0, stream>>>(h1b, as1, ad1, offs, csrS, csrE, b1,
                                        alpha1, h1eh, h1el);

    gemm_fused<512, 256, 1, true><<<dim3(313, 2), 256, 0, stream>>>(
        nullptr, h1eh, h1el, W2h, W2l, h2b, a_src2, a_dst2, as2, ad2, NNODES);
    agg2<<<NNODES * 4, 64, 0, stream>>>(h2b, as2, ad2, offs, csrS, csrE, b2,
                                        alpha2, out2);
}

// Round 8
// 363.097 us; speedup vs baseline: 1.3481x; 1.3481x over previous
//
#include <hip/hip_runtime.h>
#include <hip/hip_bf16.h>
#include <cstdint>

// SimpleGAT on MI355X. Round 8:
//   R7 @489us: XCD-sharding CONFIRMED (agg1 FETCH 156->38.5MB) but agg became
//   VALU-bound (176us, 61% VALU): softmax redone 8x/node + 2 shuffles/edge.
//   gemm1 RT=2 also halved wave count (2.4/SIMD) - occupancy regression.
// Changes:
//   1. alpha1k/alpha2k: softmax ONCE per node (1 wave/node), writes alpha
//      outputs + CSR-ordered alphaCSR.
//   2. agg1/agg2: pure gather-FMA per (node,cq) block. Inner loop: uniform
//      s_load of (src, alpha) + coalesced 128B slice gather + fmac. No
//      shuffles, no recompute. XCD shard kept (cq = blockIdx%8 / %4).
//   3. gemm: RT=1 (4.9 waves/SIMD as R6) + A-prefetch pipeline kept;
//      gemm2 A pre-split (no cvt).
//
// MFMA 16x16x32 bf16 layouts (verified R3-R7):
//   A: lane holds A[m=lane&15][k=(lane>>4)*8 + j], j=0..7
//   B: lane holds B[k=(lane>>4)*8 + j][n=lane&15]   (pre-swizzled contiguous)
//   C/D: col = lane&15, row = (lane>>4)*4 + reg

#define NNODES 20000
#define NEDGES 320000
#define ETOT   340000   // NEDGES + NNODES self loops
#define F1     512      // HEADS*HID
#define F2     256      // OUT_CH
#define HEADS  4

typedef __bf16 bf16;
typedef __attribute__((ext_vector_type(8))) __bf16 bf16x8;
typedef __attribute__((ext_vector_type(4))) float f32x4;

__device__ __forceinline__ void gload_lds16(const void* g, void* l) {
    __builtin_amdgcn_global_load_lds(
        (const __attribute__((address_space(1))) void*)g,
        (__attribute__((address_space(3))) void*)l, 16, 0, 0);
}

// ---------------- CSR build ----------------
__global__ void deg_count(const int* __restrict__ ei, int* __restrict__ deg) {
    int e = blockIdx.x * blockDim.x + threadIdx.x;
    if (e >= ETOT) return;
    int dst = (e < NEDGES) ? ei[NEDGES + e] : (e - NEDGES);
    atomicAdd(&deg[dst], 1);
}

__global__ void scan_deg(const int* __restrict__ deg, int* __restrict__ offs,
                         int* __restrict__ cur) {
    __shared__ int sums[1024];
    const int t = threadIdx.x;
    const int PER = 20;
    int base = t * PER;
    int local[PER];
    int run = 0;
#pragma unroll
    for (int j = 0; j < PER; j++) {
        int i = base + j;
        int v = (i < NNODES) ? deg[i] : 0;
        local[j] = run;
        run += v;
    }
    sums[t] = run;
    __syncthreads();
    for (int o = 1; o < 1024; o <<= 1) {
        int v = (t >= o) ? sums[t - o] : 0;
        __syncthreads();
        sums[t] += v;
        __syncthreads();
    }
    int texcl = (t == 0) ? 0 : sums[t - 1];
#pragma unroll
    for (int j = 0; j < PER; j++) {
        int i = base + j;
        if (i < NNODES) {
            int e = texcl + local[j];
            cur[i] = e;
            offs[i] = e;
        }
    }
    if (t == 1023) offs[NNODES] = sums[1023];
}

__global__ void fill_csr(const int* __restrict__ ei, int* __restrict__ cur,
                         int* __restrict__ csr_src, int* __restrict__ csr_eid) {
    int e = blockIdx.x * blockDim.x + threadIdx.x;
    if (e >= ETOT) return;
    int src, dst;
    if (e < NEDGES) { src = ei[e]; dst = ei[NEDGES + e]; }
    else            { src = dst = e - NEDGES; }
    int p = atomicAdd(&cur[dst], 1);
    csr_src[p] = src;
    csr_eid[p] = e;
}

// ---------------- W swizzle (both weights in one launch) ----------------
__device__ __forceinline__ void swz(const float* __restrict__ W, bf16* __restrict__ Wh,
                                    bf16* __restrict__ Wl, int N, int idx) {
    int lane = idx & 63;
    int tile = idx >> 6;
    int NT = N >> 4;
    int kt = tile / NT, nt = tile - kt * NT;
    int krow = kt * 32 + (lane >> 4) * 8;
    int col  = nt * 16 + (lane & 15);
    union { bf16 b[8]; uint4 u; } hi, lo;
#pragma unroll
    for (int j = 0; j < 8; j++) {
        float w = W[(size_t)(krow + j) * N + col];
        bf16 h = (bf16)w;
        hi.b[j] = h;
        lo.b[j] = (bf16)(w - (float)h);
    }
    *(uint4*)(Wh + (size_t)idx * 8) = hi.u;
    *(uint4*)(Wl + (size_t)idx * 8) = lo.u;
}

__global__ void swizzle_both(const float* __restrict__ W1, bf16* __restrict__ W1h,
                             bf16* __restrict__ W1l, const float* __restrict__ W2,
                             bf16* __restrict__ W2h, bf16* __restrict__ W2l) {
    int idx = blockIdx.x * blockDim.x + threadIdx.x;
    const int t1 = (512 * 512) >> 3;
    const int t2 = (512 * 256) >> 3;
    if (idx < t1) swz(W1, W1h, W1l, 512, idx);
    else if (idx < t1 + t2) swz(W2, W2h, W2l, 256, idx - t1);
}

// ------- split-bf16 MFMA GEMM, LDS-staged B, pipelined A, fused attn epilogue ----
// block = 4 waves x 16 rows = 64 rows; 8 col-tiles = 128 cols. LDS dbuf 2x16KB.
template <int K, int N, bool ASPLIT>
__global__ __launch_bounds__(256) void gemm_fused(const float* __restrict__ A,
                                                  const bf16* __restrict__ Ah,
                                                  const bf16* __restrict__ Al,
                                                  const bf16* __restrict__ Bh,
                                                  const bf16* __restrict__ Bl,
                                                  bf16* __restrict__ Cb,
                                                  const float* __restrict__ asrc,
                                                  const float* __restrict__ adst,
                                                  float* __restrict__ as_out,
                                                  float* __restrict__ ad_out, int M) {
    __shared__ __align__(16) char smem[2][16384];
    const int lane = threadIdx.x & 63;
    const int wave = threadIdx.x >> 6;
    const int row_base = blockIdx.x * 64 + wave * 16;
    const int colt0 = blockIdx.y * 8;
    constexpr int NT = N / 16;

    const char* hbase = (const char*)Bh + (size_t)colt0 * 1024;
    const char* lbase = (const char*)Bl + (size_t)colt0 * 1024;
    auto stage = [&](int kt, int buf) {
        size_t kb = (size_t)kt * NT * 1024;
#pragma unroll
        for (int q = 0; q < 4; q++) {
            int off = wave * 4096 + q * 1024;
            const char* src = (off < 8192) ? (hbase + kb + off)
                                           : (lbase + kb + (off - 8192));
            gload_lds16(src + lane * 16, &smem[buf][off]);
        }
    };

    int r0 = row_base + (lane & 15);
    if (r0 >= M) r0 = M - 1;
    const float* aptr = A ? (A + (size_t)r0 * K + ((lane >> 4) * 8)) : nullptr;
    const bf16* ahp = ASPLIT ? (Ah + (size_t)r0 * K + ((lane >> 4) * 8)) : nullptr;
    const bf16* alp = ASPLIT ? (Al + (size_t)r0 * K + ((lane >> 4) * 8)) : nullptr;

    float4 nf0, nf1;               // next A raw (fp32 path)
    bf16x8 nah, nal;               // next A (pre-split path)
    auto fetchA = [&](int kt) {
        if constexpr (ASPLIT) {
            nah = *(const bf16x8*)(ahp + kt * 32);
            nal = *(const bf16x8*)(alp + kt * 32);
        } else {
            nf0 = *(const float4*)(aptr + kt * 32);
            nf1 = *(const float4*)(aptr + kt * 32 + 4);
        }
    };
    bf16x8 cah, cal;
    auto cvtA = [&]() {
        if constexpr (ASPLIT) {
            cah = nah;
            cal = nal;
        } else {
            float av[8];
            *(float4*)(av)     = nf0;
            *(float4*)(av + 4) = nf1;
#pragma unroll
            for (int j = 0; j < 8; j++) {
                bf16 h = (bf16)av[j];
                cah[j] = h;
                cal[j] = (bf16)(av[j] - (float)h);
            }
        }
    };

    f32x4 acc[8] = {};
    stage(0, 0);
    fetchA(0);
    __syncthreads();
    for (int kt = 0; kt < K / 32; ++kt) {
        cvtA();                               // consumes fetchA(kt)
        if (kt + 1 < K / 32) {
            stage(kt + 1, (kt + 1) & 1);      // full compute window in flight
            fetchA(kt + 1);
        }
        const char* bb = smem[kt & 1];
#pragma unroll
        for (int c = 0; c < 8; c++) {
            bf16x8 bh = *(const bf16x8*)(bb + c * 1024 + lane * 16);
            bf16x8 bl = *(const bf16x8*)(bb + 8192 + c * 1024 + lane * 16);
            acc[c] = __builtin_amdgcn_mfma_f32_16x16x32_bf16(cah, bh, acc[c], 0, 0, 0);
            acc[c] = __builtin_amdgcn_mfma_f32_16x16x32_bf16(cah, bl, acc[c], 0, 0, 0);
            acc[c] = __builtin_amdgcn_mfma_f32_16x16x32_bf16(cal, bh, acc[c], 0, 0, 0);
        }
        __syncthreads();
    }

    const int crow0 = row_base + (lane >> 4) * 4;
    const int col15 = lane & 15;
#pragma unroll
    for (int c = 0; c < 8; c++)
#pragma unroll
        for (int r = 0; r < 4; r++) {
            int rr = crow0 + r;
            if (rr < M)
                Cb[(size_t)rr * N + (colt0 + c) * 16 + col15] = (bf16)acc[c][r];
        }

    // fused attention-coefficient dots over the block's 128 cols
    float ss[4] = {}, sd[4] = {};
#pragma unroll
    for (int c = 0; c < 8; c++) {
        int cw = blockIdx.y * 128 + c * 16 + col15;
        float was = asrc[cw];
        float wad = adst[cw];
#pragma unroll
        for (int r = 0; r < 4; r++) {
            ss[r] += acc[c][r] * was;
            sd[r] += acc[c][r] * wad;
        }
    }
#pragma unroll
    for (int o = 1; o < 16; o <<= 1)
#pragma unroll
        for (int r = 0; r < 4; r++) {
            ss[r] += __shfl_xor(ss[r], o);
            sd[r] += __shfl_xor(sd[r], o);
        }
    if (col15 == 0) {
#pragma unroll
        for (int r = 0; r < 4; r++) {
            int rr = crow0 + r;
            if (rr < M) {
                if constexpr (N == 512) {       // block cols == one head
                    as_out[rr * 4 + blockIdx.y] = ss[r];
                    ad_out[rr * 4 + blockIdx.y] = sd[r];
                } else {                         // half head: atomic reduce
                    atomicAdd(&as_out[rr], ss[r]);
                    atomicAdd(&ad_out[rr], sd[r]);
                }
            }
        }
    }
}

// -------- alpha kernels: softmax ONCE per node (1 wave/node, 4 waves/block) -----
__global__ __launch_bounds__(256) void alpha1k(const float* __restrict__ as1,
                                               const float* __restrict__ ad1,
                                               const int* __restrict__ offs,
                                               const int* __restrict__ csrS,
                                               const int* __restrict__ csrE,
                                               float* __restrict__ alpha1,
                                               float* __restrict__ aC1) {
    int n = blockIdx.x * 4 + (threadIdx.x >> 6);
    int lane = threadIdx.x & 63;
    if (n >= NNODES) return;
    int beg = offs[n], deg = offs[n + 1] - beg;

    float4 ad4 = *(const float4*)(ad1 + n * 4);
    const float adn[4] = {ad4.x, ad4.y, ad4.z, ad4.w};

    float v0[4] = {};
    int e0 = 0;
    float mx[4] = {-3e38f, -3e38f, -3e38f, -3e38f};
    for (int idx = lane; idx < deg; idx += 64) {
        int s = csrS[beg + idx];
        float4 a4 = *(const float4*)(as1 + s * 4);
        float v[4] = {a4.x + adn[0], a4.y + adn[1], a4.z + adn[2], a4.w + adn[3]};
#pragma unroll
        for (int k = 0; k < 4; k++) {
            v[k] = v[k] > 0.f ? v[k] : 0.2f * v[k];
            mx[k] = fmaxf(mx[k], v[k]);
        }
        if (idx == lane) {
            e0 = csrE[beg + idx];
#pragma unroll
            for (int k = 0; k < 4; k++) v0[k] = v[k];
        }
    }
#pragma unroll
    for (int o = 1; o < 64; o <<= 1)
#pragma unroll
        for (int k = 0; k < 4; k++) mx[k] = fmaxf(mx[k], __shfl_xor(mx[k], o));

    float ex0[4] = {0.f, 0.f, 0.f, 0.f};
    float ls[4] = {0.f, 0.f, 0.f, 0.f};
    if (lane < deg) {
#pragma unroll
        for (int k = 0; k < 4; k++) { ex0[k] = __expf(v0[k] - mx[k]); ls[k] = ex0[k]; }
    }
    for (int idx = lane + 64; idx < deg; idx += 64) {
        int s = csrS[beg + idx];
        float4 a4 = *(const float4*)(as1 + s * 4);
        float v[4] = {a4.x + adn[0], a4.y + adn[1], a4.z + adn[2], a4.w + adn[3]};
#pragma unroll
        for (int k = 0; k < 4; k++) {
            v[k] = v[k] > 0.f ? v[k] : 0.2f * v[k];
            ls[k] += __expf(v[k] - mx[k]);
        }
    }
#pragma unroll
    for (int o = 1; o < 64; o <<= 1)
#pragma unroll
        for (int k = 0; k < 4; k++) ls[k] += __shfl_xor(ls[k], o);
    float rden[4];
#pragma unroll
    for (int k = 0; k < 4; k++) rden[k] = 1.f / ls[k];

    for (int idx = lane; idx < deg; idx += 64) {
        float al[4];
        int e;
        if (idx == lane) {
            e = e0;
#pragma unroll
            for (int k = 0; k < 4; k++) al[k] = ex0[k] * rden[k];
        } else {
            int s = csrS[beg + idx];
            e = csrE[beg + idx];
            float4 a4 = *(const float4*)(as1 + s * 4);
            float v[4] = {a4.x + adn[0], a4.y + adn[1], a4.z + adn[2], a4.w + adn[3]};
#pragma unroll
            for (int k = 0; k < 4; k++) {
                v[k] = v[k] > 0.f ? v[k] : 0.2f * v[k];
                al[k] = __expf(v[k] - mx[k]) * rden[k];
            }
        }
        float4 f = make_float4(al[0], al[1], al[2], al[3]);
        *(float4*)(aC1 + (size_t)(beg + idx) * 4) = f;
        *(float4*)(alpha1 + (size_t)e * 4) = f;
    }
}

__global__ __launch_bounds__(256) void alpha2k(const float* __restrict__ as2,
                                               const float* __restrict__ ad2,
                                               const int* __restrict__ offs,
                                               const int* __restrict__ csrS,
                                               const int* __restrict__ csrE,
                                               float* __restrict__ alpha2,
                                               float* __restrict__ aC2) {
    int n = blockIdx.x * 4 + (threadIdx.x >> 6);
    int lane = threadIdx.x & 63;
    if (n >= NNODES) return;
    int beg = offs[n], deg = offs[n + 1] - beg;
    const float adn = ad2[n];

    float v0 = 0.f;
    int e0 = 0;
    float mx = -3e38f;
    for (int idx = lane; idx < deg; idx += 64) {
        int s = csrS[beg + idx];
        float v = as2[s] + adn;
        v = v > 0.f ? v : 0.2f * v;
        mx = fmaxf(mx, v);
        if (idx == lane) { e0 = csrE[beg + idx]; v0 = v; }
    }
#pragma unroll
    for (int o = 1; o < 64; o <<= 1) mx = fmaxf(mx, __shfl_xor(mx, o));

    float ex0 = 0.f, ls = 0.f;
    if (lane < deg) { ex0 = __expf(v0 - mx); ls = ex0; }
    for (int idx = lane + 64; idx < deg; idx += 64) {
        int s = csrS[beg + idx];
        float v = as2[s] + adn;
        v = v > 0.f ? v : 0.2f * v;
        ls += __expf(v - mx);
    }
#pragma unroll
    for (int o = 1; o < 64; o <<= 1) ls += __shfl_xor(ls, o);
    float rden = 1.f / ls;

    for (int idx = lane; idx < deg; idx += 64) {
        float a;
        int e;
        if (idx == lane) { e = e0; a = ex0 * rden; }
        else {
            int s = csrS[beg + idx];
            e = csrE[beg + idx];
            float v = as2[s] + adn;
            v = v > 0.f ? v : 0.2f * v;
            a = __expf(v - mx) * rden;
        }
        aC2[beg + idx] = a;
        alpha2[e] = a;
    }
}

// -------- agg1: pure gather-FMA, XCD-sharded (node, cq=0..7), 1 wave --------
// blockIdx = n*8+cq -> XCD x sees only slice cq==x (2.56MB h1b slice, L2-fit).
__global__ __launch_bounds__(64) void agg1(const bf16* __restrict__ h1b,
                                           const float* __restrict__ aC1,
                                           const int* __restrict__ offs,
                                           const int* __restrict__ csrS,
                                           const float* __restrict__ b1,
                                           bf16* __restrict__ h1eh,
                                           bf16* __restrict__ h1el) {
    const int n = blockIdx.x >> 3, cq = blockIdx.x & 7;
    const int lane = threadIdx.x;
    const int h = cq >> 1;
    const int beg = offs[n];
    const int deg = offs[n + 1] - beg;
    const int ch = (cq << 6) + lane;
    const bf16* __restrict__ hb = h1b + ch;

    float acc = 0.f;
#pragma unroll 4
    for (int i = 0; i < deg; ++i) {
        int s = csrS[beg + i];                          // uniform -> s_load
        float a = aC1[(size_t)(beg + i) * 4 + h];       // uniform -> s_load
        acc += a * (float)hb[(size_t)s * F1];
    }
    float t = acc + b1[ch];
    t = t > 0.f ? t : expm1f(t);     // ELU
    bf16 hi = (bf16)t;
    h1eh[(size_t)n * F1 + ch] = hi;
    h1el[(size_t)n * F1 + ch] = (bf16)(t - (float)hi);
}

// -------- agg2: pure gather-FMA, XCD-sharded (node, cq=0..3), final out --------
__global__ __launch_bounds__(64) void agg2(const bf16* __restrict__ h2b,
                                           const float* __restrict__ aC2,
                                           const int* __restrict__ offs,
                                           const int* __restrict__ csrS,
                                           const float* __restrict__ b2,
                                           float* __restrict__ out) {
    const int n = blockIdx.x >> 2, cq = blockIdx.x & 3;
    const int lane = threadIdx.x;
    const int beg = offs[n];
    const int deg = offs[n + 1] - beg;
    const int ch = (cq << 6) + lane;
    const bf16* __restrict__ hb = h2b + ch;

    float acc = 0.f;
#pragma unroll 4
    for (int i = 0; i < deg; ++i) {
        int s = csrS[beg + i];
        float a = aC2[beg + i];
        acc += a * (float)hb[(size_t)s * F2];
    }
    out[(size_t)n * F2 + ch] = acc + b2[ch];
}

// ---------------- launch ----------------
extern "C" void kernel_launch(void* const* d_in, const int* in_sizes, int n_in,
                              void* d_out, int out_size, void* d_ws, size_t ws_size,
                              hipStream_t stream) {
    const float* x      = (const float*)d_in[0];
    const int*   ei     = (const int*)d_in[1];
    const float* W1     = (const float*)d_in[2];
    const float* a_src1 = (const float*)d_in[3];
    const float* a_dst1 = (const float*)d_in[4];
    const float* b1     = (const float*)d_in[5];
    const float* W2     = (const float*)d_in[6];
    const float* a_src2 = (const float*)d_in[7];
    const float* a_dst2 = (const float*)d_in[8];
    const float* b2     = (const float*)d_in[9];

    char* ws = (char*)d_ws;
    size_t off = 0;
    auto alloc = [&](size_t bytes) -> char* {
        char* p = ws + off;
        off += (bytes + 255) & ~(size_t)255;
        return p;
    };
    bf16*  h1b  = (bf16*) alloc((size_t)NNODES * F1 * 2);   // 20.5 MB
    bf16*  h2b  = (bf16*) alloc((size_t)NNODES * F2 * 2);   // 10.2 MB
    bf16*  h1eh = (bf16*) alloc((size_t)NNODES * F1 * 2);   // 20.5 MB
    bf16*  h1el = (bf16*) alloc((size_t)NNODES * F1 * 2);   // 20.5 MB
    float* aC1  = (float*)alloc((size_t)ETOT * 4 * 4);      // 5.44 MB
    float* aC2  = (float*)alloc((size_t)ETOT * 4);          // 1.36 MB
    float* as1  = (float*)alloc((size_t)NNODES * 4 * 4);
    float* ad1  = (float*)alloc((size_t)NNODES * 4 * 4);
    // deg, as2, ad2 contiguous: single memset covers all three
    int*   deg  = (int*)  alloc((size_t)NNODES * 4);
    float* as2  = (float*)alloc((size_t)NNODES * 4);
    float* ad2  = (float*)alloc((size_t)NNODES * 4);
    bf16*  W1h  = (bf16*) alloc((size_t)512 * 512 * 2);
    bf16*  W1l  = (bf16*) alloc((size_t)512 * 512 * 2);
    bf16*  W2h  = (bf16*) alloc((size_t)512 * 256 * 2);
    bf16*  W2l  = (bf16*) alloc((size_t)512 * 256 * 2);
    int*   offs = (int*)  alloc((size_t)(NNODES + 1) * 4);
    int*   cur  = (int*)  alloc((size_t)NNODES * 4);
    int*   csrS = (int*)  alloc((size_t)ETOT * 4);
    int*   csrE = (int*)  alloc((size_t)ETOT * 4);

    float* out2   = (float*)d_out;                      // [20000,256]
    float* alpha1 = out2 + (size_t)NNODES * F2;         // [340000,4]
    float* alpha2 = alpha1 + (size_t)ETOT * HEADS;      // [340000]

    hipMemsetAsync(deg, 0, (size_t)((char*)ad2 - (char*)deg) + NNODES * 4, stream);
    deg_count<<<(ETOT + 255) / 256, 256, 0, stream>>>(ei, deg);
    scan_deg<<<1, 1024, 0, stream>>>(deg, offs, cur);
    fill_csr<<<(ETOT + 255) / 256, 256, 0, stream>>>(ei, cur, csrS, csrE);

    swizzle_both<<<(49152 + 255) / 256, 256, 0, stream>>>(W1, W1h, W1l, W2, W2h, W2l);

    gemm_fused<512, 512, false><<<dim3(313, 4), 256, 0, stream>>>(
        x, nullptr, nullptr, W1h, W1l, h1b, a_src1, a_dst1, as1, ad1, NNODES);
    alpha1k<<<(NNODES + 3) / 4, 256, 0, stream>>>(as1, ad1, offs, csrS, csrE,
                                                  alpha1, aC1);
    agg1<<<NNODES * 8, 64, 0, stream>>>(h1b, aC1, offs, csrS, b1, h1eh, h1el);

    gemm_fused<512, 256, true><<<dim3(313, 2), 256, 0, stream>>>(
        nullptr, h1eh, h1el, W2h, W2l, h2b, a_src2, a_dst2, as2, ad2, NNODES);
    alpha2k<<<(NNODES + 3) / 4, 256, 0, stream>>>(as2, ad2, offs, csrS, csrE,
                                                  alpha2, aC2);
    agg2<<<NNODES * 4, 64, 0, stream>>>(h2b, aC2, offs, csrS, b2, out2);
}